// Round 7
// baseline (885.487 us; speedup 1.0000x reference)
//
#include <hip/hip_runtime.h>

#define BATCH 64
#define SEQ   512
#define INPD  128
#define HID   256
#define G4    1024   // 4*HID
#define HSL   36     // h slice stride in floats (32 + 4 pad) -> conflict-free b128 reads

// 256 blocks x 512 threads, 4 blocks per batch (same-XCD via bid&7 = b>>3).
// Thread (CG = tid>>3 in [0,64): hidden unit; S = tid&7: k-slice of 32 h-rows
// + 16 x-rows). Each thread owns ALL FOUR gate columns of unit CG:
// wh[32][4], wi[16][4] = 192 f32 in regs. Per step (ONE barrier):
//   matvec: acc[g] (preloaded with x-part) += 32 h-rows from hbuf[st&1]
//   DPP butterfly allreduce over the 8 S-lanes (quad xor1/xor2 + half-mirror)
//   +bias -> branch-free cell update in ALL lanes:
//     role r=S&3 picks gate; z = sigmoid(k*x), k=2 for g-gate, z=2z-1 fix
//     zg = dpp_xor2(z) (lane0: tanh g, lane1: sig o); p = z*zg; pp = dpp_xor1(p)
//     cn = z*cs + pp (lane1 = f*c + i*g); hn = tanh(cn)*zg (lane1 valid)
//   S==1 lane: tagged atomic store -> hbuf_next/out. S in 2..4: poll 3 remote
//   units each (load-early / XPART / spin-late). All: XPART resets acc for st+1.
//   __syncthreads()
// Cross-block h exchange: step-tagged 64-bit relaxed agent-scope atomics,
// double-buffered by step parity (value-carried ordering, no fences).

template<int CTRL>
__device__ __forceinline__ float dppf(float v) {
    return __int_as_float(__builtin_amdgcn_update_dpp(
        0, __float_as_int(v), CTRL, 0xF, 0xF, true));
}
#define DPP_XOR1 0xB1   // quad_perm [1,0,3,2]
#define DPP_XOR2 0x4E   // quad_perm [2,3,0,1]
#define DPP_HMIR 0x141  // row_half_mirror: i <-> 7-i within each 8 lanes

#define HROW(h, r) { \
    a0 = fmaf(h, wh[(r)*4+0], a0); a1 = fmaf(h, wh[(r)*4+1], a1); \
    a2 = fmaf(h, wh[(r)*4+2], a2); a3 = fmaf(h, wh[(r)*4+3], a3); }

#define XROW(h, r) { \
    a0 = fmaf(h, wi[(r)*4+0], a0); a1 = fmaf(h, wi[(r)*4+1], a1); \
    a2 = fmaf(h, wi[(r)*4+2], a2); a3 = fmaf(h, wi[(r)*4+3], a3); }

#define XPART_ALL { \
    a0 = nx0.x * wi[0]; a1 = nx0.x * wi[1]; a2 = nx0.x * wi[2]; a3 = nx0.x * wi[3]; \
    XROW(nx0.y, 1)  XROW(nx0.z, 2)  XROW(nx0.w, 3) \
    XROW(nx1.x, 4)  XROW(nx1.y, 5)  XROW(nx1.z, 6)  XROW(nx1.w, 7) \
    XROW(nx2.x, 8)  XROW(nx2.y, 9)  XROW(nx2.z, 10) XROW(nx2.w, 11) \
    XROW(nx3.x, 12) XROW(nx3.y, 13) XROW(nx3.z, 14) XROW(nx3.w, 15) }

__global__ __launch_bounds__(512, 2)
void ChaoticLSTM_kernel(const float* __restrict__ x,  const float* __restrict__ Wi,
                        const float* __restrict__ Wh, const float* __restrict__ Bb,
                        float* __restrict__ out, unsigned long long* __restrict__ exch)
{
    const int bid   = blockIdx.x;
    const int xcd   = bid & 7;
    const int slotn = bid >> 3;
    const int b     = xcd * 8 + (slotn >> 2);  // batch element
    const int part  = slotn & 3;               // 64-unit chunk of H
    const int tid   = threadIdx.x;
    const int CG    = tid >> 3;                // hidden unit 0..63
    const int S     = tid & 7;                 // k-slice

    __shared__ __align__(16) float hbuf[2][8 * HSL];

    // ---- weights into registers: all 4 gate columns of unit CG ----
    float wh[128];   // [r<32][g<4] : h-rows S*32+r, col g*256+part*64+CG
    float wi[64];    // [r<16][g<4] : x-rows S*16+r
    {
        const int col = part * 64 + CG;
#pragma unroll
        for (int r = 0; r < 32; ++r) {
            const float* p = Wh + (size_t)(S * 32 + r) * G4 + col;
            wh[r*4+0] = p[0]; wh[r*4+1] = p[256]; wh[r*4+2] = p[512]; wh[r*4+3] = p[768];
        }
#pragma unroll
        for (int r = 0; r < 16; ++r) {
            const float* p = Wi + (size_t)(S * 16 + r) * G4 + col;
            wi[r*4+0] = p[0]; wi[r*4+1] = p[256]; wi[r*4+2] = p[512]; wi[r*4+3] = p[768];
        }
    }
    const float bb0 = Bb[part*64 + CG],       bb1 = Bb[256 + part*64 + CG];
    const float bb2 = Bb[512 + part*64 + CG], bb3 = Bb[768 + part*64 + CG];

    unsigned long long* __restrict__ exb = exch + (size_t)b * 512;
    const float* __restrict__ xrow = x + (size_t)b * SEQ * INPD + S * 16;

    // ---- roles ----
    const bool is_own  = (S == 1);             // holds valid hn/cs for unit CG
    const int  jglob   = part * 64 + CG;
    const bool is_poll = (S >= 2 && S <= 4);
    int pidx = 0;
    if (is_poll) {
        int p = CG * 3 + (S - 2);              // 0..191
        pidx = (((part + 1 + (p >> 6)) & 3) << 6) + (p & 63);
    }

    // ---- init ----
    float cs = 0.f, hn_keep = 0.f;
    if (tid < 256) hbuf[0][(tid >> 5) * HSL + (tid & 31)] = 0.f;
    if (tid < 64) {   // clear own exchange slots (both parities)
        __hip_atomic_store(&exb[part*64 + tid],       0ull, __ATOMIC_RELAXED, __HIP_MEMORY_SCOPE_AGENT);
        __hip_atomic_store(&exb[256 + part*64 + tid], 0ull, __ATOMIC_RELAXED, __HIP_MEMORY_SCOPE_AGENT);
    }

    float a0, a1, a2, a3;
    {   // acc = x-part for step 0
        float4 nx0 = *(const float4*)(xrow);
        float4 nx1 = *(const float4*)(xrow + 4);
        float4 nx2 = *(const float4*)(xrow + 8);
        float4 nx3 = *(const float4*)(xrow + 12);
        XPART_ALL;
    }
    __syncthreads();

    for (int st = 0; st < SEQ; ++st) {
        // x loads for st+1, issued early (consumed at XPART below)
        const float* xp = xrow + (size_t)((st + 1 < SEQ) ? st + 1 : st) * INPD;
        float4 nx0 = *(const float4*)(xp);
        float4 nx1 = *(const float4*)(xp + 4);
        float4 nx2 = *(const float4*)(xp + 8);
        float4 nx3 = *(const float4*)(xp + 12);

        // ---- h-matvec: 32 rows from hbuf[st&1] (conflict-free b128) ----
        {
            const float* hb = hbuf[st & 1] + S * HSL;
            float4 hv;
            hv = *(const float4*)(hb);      HROW(hv.x, 0)  HROW(hv.y, 1)  HROW(hv.z, 2)  HROW(hv.w, 3)
            hv = *(const float4*)(hb + 4);  HROW(hv.x, 4)  HROW(hv.y, 5)  HROW(hv.z, 6)  HROW(hv.w, 7)
            hv = *(const float4*)(hb + 8);  HROW(hv.x, 8)  HROW(hv.y, 9)  HROW(hv.z, 10) HROW(hv.w, 11)
            hv = *(const float4*)(hb + 12); HROW(hv.x, 12) HROW(hv.y, 13) HROW(hv.z, 14) HROW(hv.w, 15)
            hv = *(const float4*)(hb + 16); HROW(hv.x, 16) HROW(hv.y, 17) HROW(hv.z, 18) HROW(hv.w, 19)
            hv = *(const float4*)(hb + 20); HROW(hv.x, 20) HROW(hv.y, 21) HROW(hv.z, 22) HROW(hv.w, 23)
            hv = *(const float4*)(hb + 24); HROW(hv.x, 24) HROW(hv.y, 25) HROW(hv.z, 26) HROW(hv.w, 27)
            hv = *(const float4*)(hb + 28); HROW(hv.x, 28) HROW(hv.y, 29) HROW(hv.z, 30) HROW(hv.w, 31)
        }

        // ---- DPP butterfly allreduce over 8 S-lanes (VALU pipe) ----
        a0 += dppf<DPP_XOR1>(a0); a1 += dppf<DPP_XOR1>(a1); a2 += dppf<DPP_XOR1>(a2); a3 += dppf<DPP_XOR1>(a3);
        a0 += dppf<DPP_XOR2>(a0); a1 += dppf<DPP_XOR2>(a1); a2 += dppf<DPP_XOR2>(a2); a3 += dppf<DPP_XOR2>(a3);
        a0 += dppf<DPP_HMIR>(a0); a1 += dppf<DPP_HMIR>(a1); a2 += dppf<DPP_HMIR>(a2); a3 += dppf<DPP_HMIR>(a3);
        a0 += bb0; a1 += bb1; a2 += bb2; a3 += bb3;

        // ---- branch-free cell update (all lanes; S==1 lane is meaningful) ----
        const int r = S & 3;                   // 0:i 1:f 2:g 3:o
        float xs = (r & 1) ? ((r & 2) ? a3 : a1) : ((r & 2) ? a2 : a0);
        float kk = (r == 2) ? 2.f : 1.f;
        float e  = __expf(-kk * xs);
        float z  = __builtin_amdgcn_rcpf(1.f + e);
        z = fmaf(z, kk, 1.f - kk);             // role g: 2*sig(2x)-1 = tanh(x)
        float zg = dppf<DPP_XOR2>(z);          // lane0<-tanh(g), lane1<-sig(o)
        float p  = z * zg;                     // lane0: i*g
        float pp = dppf<DPP_XOR1>(p);          // lane1 <- i*g
        float cn = fmaf(z, cs, pp);            // lane1: f*c + i*g
        float e2 = __expf(-2.f * cn);
        float tc = fmaf(__builtin_amdgcn_rcpf(1.f + e2), 2.f, -1.f); // tanh(cn)
        float hn = tc * zg;                    // lane1: o * tanh(c')
        cs = cn;

        // ---- exchange + output + XPART (RTT hidden behind XPART) ----
        const unsigned tag = (unsigned)(st + 1);
        unsigned long long* slotp = exb + (st & 1) * 256;
        float* hbn = hbuf[(st + 1) & 1];
        if (is_own) {
            hn_keep = hn;
            unsigned long long w = ((unsigned long long)tag << 32)
                                 | (unsigned long long)__float_as_uint(hn);
            if (st + 1 < SEQ)
                __hip_atomic_store(&slotp[jglob], w, __ATOMIC_RELAXED, __HIP_MEMORY_SCOPE_AGENT);
            hbn[(jglob >> 5) * HSL + (jglob & 31)] = hn;
            out[(size_t)(b * SEQ + st) * HID + jglob] = hn;
        }
        unsigned long long v = 0;
        const bool pl = is_poll && (st + 1 < SEQ);
        if (pl) v = __hip_atomic_load(&slotp[pidx], __ATOMIC_RELAXED, __HIP_MEMORY_SCOPE_AGENT);
        if (st + 1 < SEQ) { XPART_ALL }        // reset acc to x-part of st+1
        if (pl) {
            while ((unsigned)(v >> 32) != tag)
                v = __hip_atomic_load(&slotp[pidx], __ATOMIC_RELAXED, __HIP_MEMORY_SCOPE_AGENT);
            hbn[(pidx >> 5) * HSL + (pidx & 31)] = __uint_as_float((unsigned)v);
        }
        __syncthreads();
    }

    // ---- epilogue: ht, ct ----
    if (is_own) {
        size_t base = (size_t)BATCH * SEQ * HID;
        out[base + (size_t)b * HID + jglob] = hn_keep;
        out[base + (size_t)BATCH * HID + (size_t)b * HID + jglob] = cs;
    }
}

extern "C" void kernel_launch(void* const* d_in, const int* in_sizes, int n_in,
                              void* d_out, int out_size, void* d_ws, size_t ws_size,
                              hipStream_t stream) {
    const float* x  = (const float*)d_in[0];
    const float* Wi = (const float*)d_in[1];
    const float* Wh = (const float*)d_in[2];
    const float* B  = (const float*)d_in[3];
    float* out = (float*)d_out;
    unsigned long long* exch = (unsigned long long*)d_ws;   // 64*512*8 = 256 KB

    ChaoticLSTM_kernel<<<dim3(256), dim3(512), 0, stream>>>(x, Wi, Wh, B, out, exch);
}